// Round 1
// baseline (1206.032 us; speedup 1.0000x reference)
//
#include <hip/hip_runtime.h>
#include <math.h>

// clDice loss: 16 x 1 x 1024 x 1024 fp32 inputs, scalar fp32 output.
// soft_skel = erosion chain + dilate + GELU accumulation, ITER=3.

#define HH 1024
#define WW 1024
#define NIMG 16
constexpr int IMG_ELEMS = HH * WW;          // 1048576
constexpr int TOTAL = NIMG * IMG_ELEMS;     // 16777216
constexpr int BLK = 256;
constexpr int NBLOCKS = TOTAL / BLK;        // 65536

__device__ __forceinline__ float gelu_f(float x) {
    // exact (erf) gelu, matches jax.nn.gelu(approximate=False)
    return 0.5f * x * (1.0f + erff(x * 0.70710678118654752440f));
}

// soft_erode: min over the 5-point cross (clamp-to-edge == +inf padding for min)
__global__ void erode_kernel(const float* __restrict__ in, float* __restrict__ out) {
    int idx = blockIdx.x * BLK + threadIdx.x;
    int x = idx & (WW - 1);
    int y = (idx >> 10) & (HH - 1);
    float v = in[idx];
    if (y > 0)      v = fminf(v, in[idx - WW]);
    if (y < HH - 1) v = fminf(v, in[idx + WW]);
    if (x > 0)      v = fminf(v, in[idx - 1]);
    if (x < WW - 1) v = fminf(v, in[idx + 1]);
    out[idx] = v;
}

// MODE 0: skel = gelu(prev - dilate(e))           (init)
// MODE 1: delta = gelu(prev - dilate(e)); skel += gelu(delta - skel*delta)
// MODE 2: MODE 1 + per-block partial sums of skel and skel*other
template <int MODE>
__global__ void skel_step_kernel(const float* __restrict__ prev,
                                 const float* __restrict__ e,
                                 float* __restrict__ skel,
                                 const float* __restrict__ other,
                                 float* __restrict__ part_s,
                                 float* __restrict__ part_so) {
    int idx = blockIdx.x * BLK + threadIdx.x;
    int x = idx & (WW - 1);
    int y = (idx >> 10) & (HH - 1);
    int xm = (x > 0) ? -1 : 0;
    int xp = (x < WW - 1) ? 1 : 0;
    int ym = (y > 0) ? -WW : 0;
    int yp = (y < HH - 1) ? WW : 0;
    // 3x3 max (dilate); duplicated edge taps don't change max
    float m =       e[idx + ym + xm];
    m = fmaxf(m,    e[idx + ym]);
    m = fmaxf(m,    e[idx + ym + xp]);
    m = fmaxf(m,    e[idx + xm]);
    m = fmaxf(m,    e[idx]);
    m = fmaxf(m,    e[idx + xp]);
    m = fmaxf(m,    e[idx + yp + xm]);
    m = fmaxf(m,    e[idx + yp]);
    m = fmaxf(m,    e[idx + yp + xp]);

    float delta = gelu_f(prev[idx] - m);
    float s;
    if (MODE == 0) {
        s = delta;
    } else {
        float s0 = skel[idx];
        s = s0 + gelu_f(delta - s0 * delta);
    }
    skel[idx] = s;

    if (MODE == 2) {
        float so = s * other[idx];
        // wave(64) shuffle reduce, then cross-wave via LDS
        float v1 = s, v2 = so;
        for (int o = 32; o > 0; o >>= 1) {
            v1 += __shfl_down(v1, o, 64);
            v2 += __shfl_down(v2, o, 64);
        }
        __shared__ float sh[8];
        int wave = threadIdx.x >> 6;
        int lane = threadIdx.x & 63;
        if (lane == 0) { sh[wave] = v1; sh[4 + wave] = v2; }
        __syncthreads();
        if (threadIdx.x == 0) {
            part_s[blockIdx.x]  = sh[0] + sh[1] + sh[2] + sh[3];
            part_so[blockIdx.x] = sh[4] + sh[5] + sh[6] + sh[7];
        }
    }
}

// per-sample dice sums: acc[n]=inter, acc[16+n]=sum(sigmoid(p)), acc[32+n]=sum(t)
__global__ void dice_kernel(const float* __restrict__ pred,
                            const float* __restrict__ tru,
                            float* __restrict__ acc) {
    int n = blockIdx.y;
    const float* p = pred + (size_t)n * IMG_ELEMS;
    const float* t = tru + (size_t)n * IMG_ELEMS;
    float inter = 0.f, sp = 0.f, st = 0.f;
    for (int i = blockIdx.x * BLK + threadIdx.x; i < IMG_ELEMS; i += gridDim.x * BLK) {
        float pv = 1.0f / (1.0f + expf(-p[i]));
        float tv = t[i];
        inter += pv * tv;
        sp += pv;
        st += tv;
    }
    for (int o = 32; o > 0; o >>= 1) {
        inter += __shfl_down(inter, o, 64);
        sp    += __shfl_down(sp, o, 64);
        st    += __shfl_down(st, o, 64);
    }
    __shared__ float sh[12];
    int wave = threadIdx.x >> 6;
    int lane = threadIdx.x & 63;
    if (lane == 0) { sh[wave] = inter; sh[4 + wave] = sp; sh[8 + wave] = st; }
    __syncthreads();
    if (threadIdx.x == 0) {
        atomicAdd(&acc[n],      sh[0] + sh[1] + sh[2] + sh[3]);
        atomicAdd(&acc[16 + n], sh[4] + sh[5] + sh[6] + sh[7]);
        atomicAdd(&acc[32 + n], sh[8] + sh[9] + sh[10] + sh[11]);
    }
}

// sum partials + combine into final scalar
__global__ void final_kernel(const float* __restrict__ pP_s,
                             const float* __restrict__ pP_so,
                             const float* __restrict__ pT_s,
                             const float* __restrict__ pT_so,
                             const float* __restrict__ diceAcc,
                             float* __restrict__ out) {
    float s_skelP = 0.f, s_skelP_t = 0.f, s_skelT = 0.f, s_skelT_p = 0.f;
    for (int i = threadIdx.x; i < NBLOCKS; i += BLK) {
        s_skelP   += pP_s[i];
        s_skelP_t += pP_so[i];
        s_skelT   += pT_s[i];
        s_skelT_p += pT_so[i];
    }
    for (int o = 32; o > 0; o >>= 1) {
        s_skelP   += __shfl_down(s_skelP, o, 64);
        s_skelP_t += __shfl_down(s_skelP_t, o, 64);
        s_skelT   += __shfl_down(s_skelT, o, 64);
        s_skelT_p += __shfl_down(s_skelT_p, o, 64);
    }
    __shared__ float sh[16];
    int wave = threadIdx.x >> 6;
    int lane = threadIdx.x & 63;
    if (lane == 0) {
        sh[wave] = s_skelP; sh[4 + wave] = s_skelP_t;
        sh[8 + wave] = s_skelT; sh[12 + wave] = s_skelT_p;
    }
    __syncthreads();
    if (threadIdx.x == 0) {
        float sumP  = sh[0] + sh[1] + sh[2] + sh[3];
        float sumPt = sh[4] + sh[5] + sh[6] + sh[7];
        float sumT  = sh[8] + sh[9] + sh[10] + sh[11];
        float sumTp = sh[12] + sh[13] + sh[14] + sh[15];

        const float SMOOTH = 1.0f;
        float tprec = (sumPt + SMOOTH) / (sumP + SMOOTH);
        float tsens = (sumTp + SMOOTH) / (sumT + SMOOTH);
        float cl_dice = 1.0f - 2.0f * (tprec * tsens) / (tprec + tsens);

        const float EPS = 1e-4f;
        float dsum = 0.f;
        for (int n = 0; n < NIMG; n++) {
            float inter = diceAcc[n];
            float sp = diceAcc[16 + n];
            float st = diceAcc[32 + n];
            float gd = (2.0f * inter + EPS) / (sp + st + EPS);
            dsum += 1.0f - gd;
        }
        float dice = dsum / (float)NIMG;
        out[0] = 0.5f * cl_dice + 0.5f * dice;
    }
}

static void run_skel_phase(const float* X, const float* other, float* skel,
                           float* eA, float* eB, float* part_s, float* part_so,
                           hipStream_t stream) {
    dim3 grd(NBLOCKS), blk(BLK);
    // e1 = erode(X); skel = gelu(X - dilate(e1))
    erode_kernel<<<grd, blk, 0, stream>>>(X, eA);
    skel_step_kernel<0><<<grd, blk, 0, stream>>>(X, eA, skel, nullptr, nullptr, nullptr);
    // iter 1
    erode_kernel<<<grd, blk, 0, stream>>>(eA, eB);
    skel_step_kernel<1><<<grd, blk, 0, stream>>>(eA, eB, skel, nullptr, nullptr, nullptr);
    // iter 2
    erode_kernel<<<grd, blk, 0, stream>>>(eB, eA);
    skel_step_kernel<1><<<grd, blk, 0, stream>>>(eB, eA, skel, nullptr, nullptr, nullptr);
    // iter 3 (+ fused global reduction of skel and skel*other)
    erode_kernel<<<grd, blk, 0, stream>>>(eA, eB);
    skel_step_kernel<2><<<grd, blk, 0, stream>>>(eA, eB, skel, other, part_s, part_so);
}

extern "C" void kernel_launch(void* const* d_in, const int* in_sizes, int n_in,
                              void* d_out, int out_size, void* d_ws, size_t ws_size,
                              hipStream_t stream) {
    const float* y_pred = (const float*)d_in[0];
    const float* y_true = (const float*)d_in[1];
    float* out = (float*)d_out;

    float* skel   = (float*)d_ws;
    float* eA     = skel + TOTAL;
    float* eB     = eA + TOTAL;
    float* pP_s   = eB + TOTAL;
    float* pP_so  = pP_s + NBLOCKS;
    float* pT_s   = pP_so + NBLOCKS;
    float* pT_so  = pT_s + NBLOCKS;
    float* diceAcc = pT_so + NBLOCKS;   // 48 floats

    hipMemsetAsync(diceAcc, 0, 48 * sizeof(float), stream);

    // skel_pred phase (reduces skel_pred and skel_pred*y_true)
    run_skel_phase(y_pred, y_true, skel, eA, eB, pP_s, pP_so, stream);
    // skel_true phase (reduces skel_true and skel_true*y_pred)
    run_skel_phase(y_true, y_pred, skel, eA, eB, pT_s, pT_so, stream);

    // dice per-sample sums
    dice_kernel<<<dim3(32, NIMG), BLK, 0, stream>>>(y_pred, y_true, diceAcc);

    // combine
    final_kernel<<<1, BLK, 0, stream>>>(pP_s, pP_so, pT_s, pT_so, diceAcc, out);
}